// Round 1
// baseline (292.065 us; speedup 1.0000x reference)
//
#include <hip/hip_runtime.h>
#include <hip/hip_bf16.h>
#include <stdint.h>

typedef unsigned short u16;
typedef unsigned int u32;
typedef __bf16 bf16x8 __attribute__((ext_vector_type(8)));
typedef float f32x4 __attribute__((ext_vector_type(4)));

#define LOG2E 1.4426950408889634f

__device__ __forceinline__ u16 f2bf(float f) {
  u32 u = __builtin_bit_cast(u32, f);
  u += 0x7FFFu + ((u >> 16) & 1u);
  return (u16)(u >> 16);
}

__device__ __forceinline__ float bf2f(u16 h) {
  u32 u = ((u32)h) << 16;
  return __builtin_bit_cast(float, u);
}

__device__ __forceinline__ void gload_lds16(const void* g, void* l) {
  __builtin_amdgcn_global_load_lds(
      (const __attribute__((address_space(1))) u32*)g,
      (__attribute__((address_space(3))) u32*)l, 16, 0, 0);
}

// ---------------- convert / concat ----------------
// xyb[s][d] bf16, s in [0,16384): b = s>>11, r = s&2047; r<1024 -> x else y
__global__ void k_concat_bf16(const float* __restrict__ x, const float* __restrict__ y,
                              u16* __restrict__ xyb) {
  int tid = blockIdx.x * blockDim.x + threadIdx.x;  // 2,097,152 threads
  int e = tid * 4;
  int s = e >> 9;
  int d = e & 511;
  int b = s >> 11, r = s & 2047;
  const float* src = (r < 1024) ? (x + ((size_t)(b * 1024 + r) * 512 + d))
                                : (y + ((size_t)(b * 1024 + (r - 1024)) * 512 + d));
  float4 v = *(const float4*)src;
  ushort4 o;
  o.x = f2bf(v.x); o.y = f2bf(v.y); o.z = f2bf(v.z); o.w = f2bf(v.w);
  *(ushort4*)(xyb + e) = o;
}

__global__ void k_f32_to_bf16(const float* __restrict__ src, u16* __restrict__ dst) {
  int tid = blockIdx.x * blockDim.x + threadIdx.x;
  int e = tid * 4;
  float4 v = *(const float4*)(src + e);
  ushort4 o;
  o.x = f2bf(v.x); o.y = f2bf(v.y); o.z = f2bf(v.z); o.w = f2bf(v.w);
  *(ushort4*)(dst + e) = o;
}

// ---------------- GEMM: C[M][N] = A[MxK] * B[NxK]^T (both row-major, k contiguous) ----------------
// m97 structure: 128x128 tile, BK=32, 4 waves (2x2), 16x16x32 bf16 MFMA.
__global__ __launch_bounds__(256) void k_gemm_bt(
    const u16* __restrict__ A, const u16* __restrict__ B, u16* __restrict__ C,
    int M, int N, int K, int ntiles) {
  __shared__ u16 As[128 * 32];
  __shared__ u16 Bs[128 * 32];
  int tm = (blockIdx.x / ntiles) * 128;
  int tn = (blockIdx.x % ntiles) * 128;
  int t = threadIdx.x;
  int lane = t & 63;
  int w = t >> 6;
  int wr = w >> 1, wc = w & 1;

  f32x4 acc[4][4] = {};

  const char* Ab = (const char*)A + (size_t)tm * K * 2;
  const char* Bb = (const char*)B + (size_t)tn * K * 2;
  int lr = t >> 2;            // staging row (i=0)
  int lc = (t & 3) * 16;      // byte col in 64B row
  size_t rowstride = (size_t)K * 2;

  for (int kt = 0; kt < (K >> 5); ++kt) {
    int kb = kt * 64;
#pragma unroll
    for (int i = 0; i < 2; ++i) {
      int row = i * 64 + lr;
      gload_lds16(Ab + (size_t)row * rowstride + kb + lc, (char*)As + row * 64 + lc);
      gload_lds16(Bb + (size_t)row * rowstride + kb + lc, (char*)Bs + row * 64 + lc);
    }
    __syncthreads();
    int ko = (lane >> 4) << 4;
    bf16x8 a[4], b[4];
#pragma unroll
    for (int mi = 0; mi < 4; ++mi)
      a[mi] = *(const bf16x8*)((const char*)As + (64 * wr + 16 * mi + (lane & 15)) * 64 + ko);
#pragma unroll
    for (int ni = 0; ni < 4; ++ni)
      b[ni] = *(const bf16x8*)((const char*)Bs + (64 * wc + 16 * ni + (lane & 15)) * 64 + ko);
#pragma unroll
    for (int mi = 0; mi < 4; ++mi)
#pragma unroll
      for (int ni = 0; ni < 4; ++ni)
        acc[mi][ni] = __builtin_amdgcn_mfma_f32_16x16x32_bf16(a[mi], b[ni], acc[mi][ni], 0, 0, 0);
    __syncthreads();
  }
#pragma unroll
  for (int mi = 0; mi < 4; ++mi) {
    int rm = tm + 64 * wr + 16 * mi + ((lane >> 4) << 2);
#pragma unroll
    for (int ni = 0; ni < 4; ++ni) {
      int cn = tn + 64 * wc + 16 * ni + (lane & 15);
#pragma unroll
      for (int r = 0; r < 4; ++r)
        C[(size_t)(rm + r) * N + cn] = f2bf(acc[mi][ni][r]);
    }
  }
}

// ---------------- flash attention ----------------
// Q,K: [16384][512] bf16 row-major. VT: [512][16384] bf16 (d-major, key contiguous).
// out: [16384][512] f32. Per block: batch b = blockIdx&7, q-tile = blockIdx>>3 (64 rows).
#define QB 64
#define KVB 64
__global__ __launch_bounds__(512) void k_flash(
    const u16* __restrict__ Q, const u16* __restrict__ K, const u16* __restrict__ VT,
    float* __restrict__ out) {
  __shared__ u16 Qs[QB * 512];   // swizzled rows of 1024B: byte ^= ((row&7)<<4)
  __shared__ u16 Ks[KVB * 512];  // same swizzle
  __shared__ float Ss[QB][68];   // padded
  __shared__ u16 Ps[QB * KVB];   // swizzled rows of 128B: byte ^= ((row&7)<<4)
  __shared__ float m_s[QB], l_s[QB], f_s[QB];

  int t = threadIdx.x;
  int lane = t & 63;
  int w = t >> 6;
  int wr = w >> 2, wc = w & 3;  // wr: q-rows 32*wr ; wc: d-slice 128*wc
  int b = blockIdx.x & 7;
  int qt = blockIdx.x >> 3;
  size_t qrow0 = (size_t)b * 2048 + (size_t)qt * QB;

  // stage Q tile (pre-swizzled global source -> linear LDS dest == swizzled logical layout)
  {
    const char* Qg = (const char*)Q + qrow0 * 1024;
#pragma unroll
    for (int i = 0; i < 8; ++i) {
      int o = i * 8192 + t * 16;
      int row = o >> 10;
      int cb = o & 1023;
      int scb = cb ^ ((row & 7) << 4);
      gload_lds16(Qg + (size_t)row * 1024 + scb, (char*)Qs + o);
    }
  }
  if (t < QB) { m_s[t] = -1e30f; l_s[t] = 0.0f; }

  f32x4 o_acc[2][8] = {};
  const char* Kgb = (const char*)K + ((size_t)b * 2048) * 1024;

  for (int it = 0; it < 2048 / KVB; ++it) {
    // stage K tile
    {
      const char* Kg = Kgb + (size_t)it * KVB * 1024;
#pragma unroll
      for (int i = 0; i < 8; ++i) {
        int o = i * 8192 + t * 16;
        int row = o >> 10;
        int cb = o & 1023;
        int scb = cb ^ ((row & 7) << 4);
        gload_lds16(Kg + (size_t)row * 1024 + scb, (char*)Ks + o);
      }
    }
    __syncthreads();

    // S = scale * Q K^T ; wave computes rows [32wr,32wr+32), keys [16wc,16wc+16)
    {
      f32x4 s_acc[2] = {};
      int krow = 16 * wc + (lane & 15);
      int qlo = lane & 15;
      int kchunk = (lane >> 4) << 4;
#pragma unroll
      for (int kk = 0; kk < 16; ++kk) {
        int kb = kk * 64 + kchunk;
        bf16x8 bfr = *(const bf16x8*)((const char*)Ks + krow * 1024 + (kb ^ ((krow & 7) << 4)));
#pragma unroll
        for (int mi = 0; mi < 2; ++mi) {
          int qrow = 32 * wr + 16 * mi + qlo;
          bf16x8 afr = *(const bf16x8*)((const char*)Qs + qrow * 1024 + (kb ^ ((qrow & 7) << 4)));
          s_acc[mi] = __builtin_amdgcn_mfma_f32_16x16x32_bf16(afr, bfr, s_acc[mi], 0, 0, 0);
        }
      }
      const float scale = 0.044194173824159216f;  // 1/sqrt(512)
#pragma unroll
      for (int mi = 0; mi < 2; ++mi) {
        int r0 = 32 * wr + 16 * mi + ((lane >> 4) << 2);
        int c = 16 * wc + (lane & 15);
#pragma unroll
        for (int r = 0; r < 4; ++r) Ss[r0 + r][c] = s_acc[mi][r] * scale;
      }
    }
    __syncthreads();

    // online softmax: 8 threads per q-row
    {
      int row = t >> 3, sub = t & 7;
      float4 v0 = *(const float4*)&Ss[row][sub * 8];
      float4 v1 = *(const float4*)&Ss[row][sub * 8 + 4];
      float s0 = v0.x, s1 = v0.y, s2 = v0.z, s3 = v0.w;
      float s4 = v1.x, s5 = v1.y, s6 = v1.z, s7 = v1.w;
      float mx = fmaxf(fmaxf(fmaxf(s0, s1), fmaxf(s2, s3)),
                       fmaxf(fmaxf(s4, s5), fmaxf(s6, s7)));
      mx = fmaxf(mx, __shfl_xor(mx, 1, 8));
      mx = fmaxf(mx, __shfl_xor(mx, 2, 8));
      mx = fmaxf(mx, __shfl_xor(mx, 4, 8));
      float m_old = m_s[row];
      float m_new = fmaxf(m_old, mx);
      float sv[8] = {s0, s1, s2, s3, s4, s5, s6, s7};
      u16 pb[8];
      float sum = 0.0f;
#pragma unroll
      for (int j = 0; j < 8; ++j) {
        float e = exp2f((sv[j] - m_new) * LOG2E);
        pb[j] = f2bf(e);
        sum += bf2f(pb[j]);  // sum the rounded values so O/l is unbiased
      }
      sum += __shfl_xor(sum, 1, 8);
      sum += __shfl_xor(sum, 2, 8);
      sum += __shfl_xor(sum, 4, 8);
      if (sub == 0) {
        float fac = exp2f((m_old - m_new) * LOG2E);
        m_s[row] = m_new;
        l_s[row] = l_s[row] * fac + sum;
        f_s[row] = fac;
      }
      u32 w0 = (u32)pb[0] | ((u32)pb[1] << 16);
      u32 w1 = (u32)pb[2] | ((u32)pb[3] << 16);
      u32 w2 = (u32)pb[4] | ((u32)pb[5] << 16);
      u32 w3 = (u32)pb[6] | ((u32)pb[7] << 16);
      uint4 pk; pk.x = w0; pk.y = w1; pk.z = w2; pk.w = w3;
      int byteoff = (row * 128 + sub * 16) ^ ((row & 7) << 4);
      *(uint4*)((char*)Ps + byteoff) = pk;
    }
    __syncthreads();

    // rescale O and accumulate PV ; wave: rows [32wr,+32), d [128wc,+128)
    {
#pragma unroll
      for (int mi = 0; mi < 2; ++mi) {
        int r0 = 32 * wr + 16 * mi + ((lane >> 4) << 2);
#pragma unroll
        for (int r = 0; r < 4; ++r) {
          float fac = f_s[r0 + r];
#pragma unroll
          for (int ni = 0; ni < 8; ++ni) o_acc[mi][ni][r] *= fac;
        }
      }
      size_t kgbase = (size_t)b * 2048 + (size_t)it * KVB + ((lane >> 4) << 3);
#pragma unroll
      for (int kk = 0; kk < 2; ++kk) {
        bf16x8 pa[2];
#pragma unroll
        for (int mi = 0; mi < 2; ++mi) {
          int prow = 32 * wr + 16 * mi + (lane & 15);
          int pboff = (prow * 128 + kk * 64 + ((lane >> 4) << 4)) ^ ((prow & 7) << 4);
          pa[mi] = *(const bf16x8*)((const char*)Ps + pboff);
        }
        size_t kg = kgbase + kk * 32;
#pragma unroll
        for (int ni = 0; ni < 8; ++ni) {
          int d = 128 * wc + 16 * ni + (lane & 15);
          bf16x8 vfr = *(const bf16x8*)((const char*)VT + ((size_t)d * 16384 + kg) * 2);
#pragma unroll
          for (int mi = 0; mi < 2; ++mi)
            o_acc[mi][ni] = __builtin_amdgcn_mfma_f32_16x16x32_bf16(pa[mi], vfr, o_acc[mi][ni], 0, 0, 0);
        }
      }
    }
  }

  // epilogue: out = O / l
  float* Ob = out + qrow0 * 512;
#pragma unroll
  for (int mi = 0; mi < 2; ++mi) {
    int r0 = 32 * wr + 16 * mi + ((lane >> 4) << 2);
#pragma unroll
    for (int r = 0; r < 4; ++r) {
      float inv = 1.0f / l_s[r0 + r];
#pragma unroll
      for (int ni = 0; ni < 8; ++ni) {
        int d = 128 * wc + 16 * ni + (lane & 15);
        Ob[(size_t)(r0 + r) * 512 + d] = o_acc[mi][ni][r] * inv;
      }
    }
  }
}

extern "C" void kernel_launch(void* const* d_in, const int* in_sizes, int n_in,
                              void* d_out, int out_size, void* d_ws, size_t ws_size,
                              hipStream_t stream) {
  const float* x = (const float*)d_in[0];
  const float* y = (const float*)d_in[1];
  const float* Wq = (const float*)d_in[2];
  const float* Wk = (const float*)d_in[3];
  const float* Wv = (const float*)d_in[4];
  float* out = (float*)d_out;

  char* ws = (char*)d_ws;
  u16* xyb = (u16*)ws; ws += (size_t)16384 * 512 * 2;
  u16* Wqb = (u16*)ws; ws += (size_t)512 * 512 * 2;
  u16* Wkb = (u16*)ws; ws += (size_t)512 * 512 * 2;
  u16* Wvb = (u16*)ws; ws += (size_t)512 * 512 * 2;
  u16* Qb  = (u16*)ws; ws += (size_t)16384 * 512 * 2;
  u16* Kb  = (u16*)ws; ws += (size_t)16384 * 512 * 2;
  u16* VTb = (u16*)ws; ws += (size_t)512 * 16384 * 2;

  // converts
  k_concat_bf16<<<8192, 256, 0, stream>>>(x, y, xyb);
  k_f32_to_bf16<<<256, 256, 0, stream>>>(Wq, Wqb);
  k_f32_to_bf16<<<256, 256, 0, stream>>>(Wk, Wkb);
  k_f32_to_bf16<<<256, 256, 0, stream>>>(Wv, Wvb);

  // projections: Q = xy Wq^T, K = xy Wk^T  (C row-major [16384][512])
  k_gemm_bt<<<128 * 4, 256, 0, stream>>>(xyb, Wqb, Qb, 16384, 512, 512, 4);
  k_gemm_bt<<<128 * 4, 256, 0, stream>>>(xyb, Wkb, Kb, 16384, 512, 512, 4);
  // VT = Wv xy^T  (C row-major [512][16384] == V transposed, key-contiguous)
  k_gemm_bt<<<4 * 128, 256, 0, stream>>>(Wvb, xyb, VTb, 512, 16384, 512, 128);

  // attention
  k_flash<<<256, 512, 0, stream>>>(Qb, Kb, VTb, out);
}

// Round 2
// 210.434 us; speedup vs baseline: 1.3879x; 1.3879x over previous
//
#include <hip/hip_runtime.h>
#include <hip/hip_bf16.h>
#include <stdint.h>

typedef unsigned short u16;
typedef unsigned int u32;
typedef __bf16 bf16x8 __attribute__((ext_vector_type(8)));
typedef _Float16 f16x8 __attribute__((ext_vector_type(8)));
typedef float f32x4 __attribute__((ext_vector_type(4)));

#define LOG2E 1.4426950408889634f

__device__ __forceinline__ u16 f2bf(float f) {
  u32 u = __builtin_bit_cast(u32, f);
  u += 0x7FFFu + ((u >> 16) & 1u);
  return (u16)(u >> 16);
}

__device__ __forceinline__ void gload_lds16(const void* g, void* l) {
  __builtin_amdgcn_global_load_lds(
      (const __attribute__((address_space(1))) u32*)g,
      (__attribute__((address_space(3))) u32*)l, 16, 0, 0);
}

// ---------------- convert / concat ----------------
__global__ void k_concat_bf16(const float* __restrict__ x, const float* __restrict__ y,
                              u16* __restrict__ xyb) {
  int tid = blockIdx.x * blockDim.x + threadIdx.x;
  int e = tid * 4;
  int s = e >> 9;
  int d = e & 511;
  int b = s >> 11, r = s & 2047;
  const float* src = (r < 1024) ? (x + ((size_t)(b * 1024 + r) * 512 + d))
                                : (y + ((size_t)(b * 1024 + (r - 1024)) * 512 + d));
  float4 v = *(const float4*)src;
  ushort4 o;
  o.x = f2bf(v.x); o.y = f2bf(v.y); o.z = f2bf(v.z); o.w = f2bf(v.w);
  *(ushort4*)(xyb + e) = o;
}

__global__ void k_f32_to_bf16(const float* __restrict__ src, u16* __restrict__ dst) {
  int tid = blockIdx.x * blockDim.x + threadIdx.x;
  int e = tid * 4;
  float4 v = *(const float4*)(src + e);
  ushort4 o;
  o.x = f2bf(v.x); o.y = f2bf(v.y); o.z = f2bf(v.z); o.w = f2bf(v.w);
  *(ushort4*)(dst + e) = o;
}

// ---------------- generalized batched GEMM: C = scale * A * B^T ----------------
// A: [bz][M][K] elem-stride lda, batch stride sA (u16-sized elems, bf16 or f16 per ABF16)
// B: [bz][N][K] elem-stride ldb, batch stride sB
// C: [bz][M][N] elem-stride ldc, batch stride sC; OUTM: 0=bf16, 1=f16, 2=f32
// m97 structure: 128x128 tile, BK=32, 4 waves (2x2), 16x16x32 MFMA.
template <int ABF16, int OUTM>
__global__ __launch_bounds__(256) void k_gemm(
    const u16* __restrict__ A, const u16* __restrict__ B, void* __restrict__ Cv,
    int lda, int ldb, int ldc,
    long long sA, long long sB, long long sC,
    int K, float scale) {
  __shared__ u16 As[128 * 32];
  __shared__ u16 Bs[128 * 32];
  int t = threadIdx.x;
  int lane = t & 63;
  int w = t >> 6;
  int wr = w >> 1, wc = w & 1;
  long long bz = blockIdx.z;

  const char* Ab = (const char*)(A + bz * sA + (size_t)blockIdx.x * 128 * lda);
  const char* Bb = (const char*)(B + bz * sB + (size_t)blockIdx.y * 128 * ldb);

  f32x4 acc[4][4] = {};
  int lr = t >> 2;        // staging row (i=0)
  int lc = (t & 3) * 16;  // byte col within 64B k-slice
  size_t rsA = (size_t)lda * 2, rsB = (size_t)ldb * 2;

  for (int kt = 0; kt < (K >> 5); ++kt) {
    int kb = kt * 64;
#pragma unroll
    for (int i = 0; i < 2; ++i) {
      int row = i * 64 + lr;
      gload_lds16(Ab + (size_t)row * rsA + kb + lc, (char*)As + row * 64 + lc);
      gload_lds16(Bb + (size_t)row * rsB + kb + lc, (char*)Bs + row * 64 + lc);
    }
    __syncthreads();
    int ko = (lane >> 4) << 4;
    bf16x8 a[4], b[4];
#pragma unroll
    for (int mi = 0; mi < 4; ++mi)
      a[mi] = *(const bf16x8*)((const char*)As + (64 * wr + 16 * mi + (lane & 15)) * 64 + ko);
#pragma unroll
    for (int ni = 0; ni < 4; ++ni)
      b[ni] = *(const bf16x8*)((const char*)Bs + (64 * wc + 16 * ni + (lane & 15)) * 64 + ko);
#pragma unroll
    for (int mi = 0; mi < 4; ++mi)
#pragma unroll
      for (int ni = 0; ni < 4; ++ni) {
        if constexpr (ABF16) {
          acc[mi][ni] = __builtin_amdgcn_mfma_f32_16x16x32_f16(
              __builtin_bit_cast(f16x8, a[mi]), __builtin_bit_cast(f16x8, b[ni]),
              acc[mi][ni], 0, 0, 0);
        } else {
          acc[mi][ni] = __builtin_amdgcn_mfma_f32_16x16x32_bf16(a[mi], b[ni], acc[mi][ni], 0, 0, 0);
        }
      }
    __syncthreads();
  }

  int rm0 = blockIdx.x * 128 + 64 * wr;
  int cn0 = blockIdx.y * 128 + 64 * wc;
#pragma unroll
  for (int mi = 0; mi < 4; ++mi) {
    int rm = rm0 + 16 * mi + ((lane >> 4) << 2);
#pragma unroll
    for (int ni = 0; ni < 4; ++ni) {
      int cn = cn0 + 16 * ni + (lane & 15);
#pragma unroll
      for (int r = 0; r < 4; ++r) {
        float v = acc[mi][ni][r] * scale;
        size_t idx = (size_t)bz * sC + (size_t)(rm + r) * ldc + cn;
        if constexpr (OUTM == 0) ((u16*)Cv)[idx] = f2bf(v);
        else if constexpr (OUTM == 1) ((_Float16*)Cv)[idx] = (_Float16)v;
        else ((float*)Cv)[idx] = v;
      }
    }
  }
}

// ---------------- row softmax, f16 in-place, rows of 2048 ----------------
// one wave per row; block = 4 waves = 4 rows
__global__ __launch_bounds__(256) void k_softmax_f16(_Float16* __restrict__ S) {
  int row = blockIdx.x * 4 + (threadIdx.x >> 6);
  int lane = threadIdx.x & 63;
  _Float16* Sr = S + (size_t)row * 2048;

  f16x8 v[4];
#pragma unroll
  for (int i = 0; i < 4; ++i) v[i] = *(const f16x8*)(Sr + i * 512 + lane * 8);

  float f[32];
#pragma unroll
  for (int i = 0; i < 4; ++i)
#pragma unroll
    for (int j = 0; j < 8; ++j) f[i * 8 + j] = (float)v[i][j];

  float mx = f[0];
#pragma unroll
  for (int i = 1; i < 32; ++i) mx = fmaxf(mx, f[i]);
#pragma unroll
  for (int off = 1; off < 64; off <<= 1) mx = fmaxf(mx, __shfl_xor(mx, off));

  float sum = 0.0f;
#pragma unroll
  for (int i = 0; i < 32; ++i) {
    f[i] = exp2f((f[i] - mx) * LOG2E);
    sum += f[i];
  }
#pragma unroll
  for (int off = 1; off < 64; off <<= 1) sum += __shfl_xor(sum, off);

  float inv = 1.0f / sum;
  f16x8 o[4];
#pragma unroll
  for (int i = 0; i < 4; ++i)
#pragma unroll
    for (int j = 0; j < 8; ++j) o[i][j] = (_Float16)(f[i * 8 + j] * inv);
#pragma unroll
  for (int i = 0; i < 4; ++i) *(f16x8*)(Sr + i * 512 + lane * 8) = o[i];
}

extern "C" void kernel_launch(void* const* d_in, const int* in_sizes, int n_in,
                              void* d_out, int out_size, void* d_ws, size_t ws_size,
                              hipStream_t stream) {
  const float* x = (const float*)d_in[0];
  const float* y = (const float*)d_in[1];
  const float* Wq = (const float*)d_in[2];
  const float* Wk = (const float*)d_in[3];
  const float* Wv = (const float*)d_in[4];
  float* out = (float*)d_out;

  const size_t SZQ = (size_t)16384 * 512 * 2;  // 16.78 MB
  char* p = (char*)d_ws;
  u16* Qb = (u16*)p; p += SZQ;
  u16* Kb = (u16*)p; p += SZQ;
  u16* VTh = (u16*)p; p += SZQ;  // f16 payload, u16-typed for GEMM arg
  u16* Wqb = (u16*)p; p += (size_t)512 * 512 * 2;
  u16* Wkb = (u16*)p; p += (size_t)512 * 512 * 2;
  u16* Wvb = (u16*)p; p += (size_t)512 * 512 * 2;
  // xyb and S share this region: xyb dead before S is first written (GEMM1 reads only Q,K)
  size_t base = (size_t)(p - (char*)d_ws);
  u16* xyb = (u16*)p;
  _Float16* Sb = (_Float16*)p;

  // chunking over q-rows if workspace is small; S chunk = 8 * (2048/nc) * 2048 * 2 bytes
  int nc;
  if (ws_size >= base + (size_t)16384 * 2048 * 2) nc = 1;
  else if (ws_size >= base + (size_t)8192 * 2048 * 2) nc = 2;
  else nc = 4;
  int mrows = 2048 / nc;  // q-rows per batch per chunk

  // converts
  k_concat_bf16<<<8192, 256, 0, stream>>>(x, y, xyb);
  k_f32_to_bf16<<<256, 256, 0, stream>>>(Wq, Wqb);
  k_f32_to_bf16<<<256, 256, 0, stream>>>(Wk, Wkb);
  k_f32_to_bf16<<<256, 256, 0, stream>>>(Wv, Wvb);

  // projections (bf16 in): Q = xy Wq^T, K = xy Wk^T (bf16 out); VT = Wv xy^T (f16 out)
  k_gemm<0, 0><<<dim3(128, 4, 1), 256, 0, stream>>>(xyb, Wqb, Qb, 512, 512, 512, 0, 0, 0, 512, 1.0f);
  k_gemm<0, 0><<<dim3(128, 4, 1), 256, 0, stream>>>(xyb, Wkb, Kb, 512, 512, 512, 0, 0, 0, 512, 1.0f);
  k_gemm<0, 1><<<dim3(4, 128, 1), 256, 0, stream>>>(Wvb, xyb, VTh, 512, 512, 16384, 0, 0, 0, 512, 1.0f);

  const float scale = 0.044194173824159216f;  // 1/sqrt(512)
  for (int c = 0; c < nc; ++c) {
    const u16* Qc = Qb + (size_t)c * mrows * 512;
    // S = scale * Qc K^T   (f16 out), per-batch: [mrows][2048]
    k_gemm<0, 1><<<dim3(mrows / 128, 16, 8), 256, 0, stream>>>(
        Qc, Kb, Sb, 512, 512, 2048,
        (long long)2048 * 512, (long long)2048 * 512, (long long)mrows * 2048,
        512, scale);
    // softmax in place
    k_softmax_f16<<<(16384 / nc) / 4, 256, 0, stream>>>(Sb);
    // O = P VT^T (f16 in, f32 out) -> d_out
    k_gemm<1, 2><<<dim3(mrows / 128, 4, 8), 256, 0, stream>>>(
        (const u16*)Sb, VTh, out + (size_t)c * mrows * 512, 2048, 16384, 512,
        (long long)mrows * 2048, (long long)2048, (long long)2048 * 512,
        2048, 1.0f);
  }
}

// Round 3
// 170.968 us; speedup vs baseline: 1.7083x; 1.2308x over previous
//
#include <hip/hip_runtime.h>
#include <hip/hip_bf16.h>
#include <stdint.h>

typedef unsigned short u16;
typedef unsigned int u32;
typedef __bf16 bf16x8 __attribute__((ext_vector_type(8)));
typedef _Float16 f16x8 __attribute__((ext_vector_type(8)));
typedef float f32x4 __attribute__((ext_vector_type(4)));

#define LOG2E 1.4426950408889634f

__device__ __forceinline__ u16 f2bf(float f) {
  u32 u = __builtin_bit_cast(u32, f);
  u += 0x7FFFu + ((u >> 16) & 1u);
  return (u16)(u >> 16);
}

__device__ __forceinline__ void gload_lds16(const void* g, void* l) {
  __builtin_amdgcn_global_load_lds(
      (const __attribute__((address_space(1))) u32*)g,
      (__attribute__((address_space(3))) u32*)l, 16, 0, 0);
}

// ---------------- convert / concat ----------------
__global__ void k_concat_bf16(const float* __restrict__ x, const float* __restrict__ y,
                              u16* __restrict__ xyb) {
  int tid = blockIdx.x * blockDim.x + threadIdx.x;
  int e = tid * 4;
  int s = e >> 9;
  int d = e & 511;
  int b = s >> 11, r = s & 2047;
  const float* src = (r < 1024) ? (x + ((size_t)(b * 1024 + r) * 512 + d))
                                : (y + ((size_t)(b * 1024 + (r - 1024)) * 512 + d));
  float4 v = *(const float4*)src;
  ushort4 o;
  o.x = f2bf(v.x); o.y = f2bf(v.y); o.z = f2bf(v.z); o.w = f2bf(v.w);
  *(ushort4*)(xyb + e) = o;
}

__global__ void k_f32_to_bf16(const float* __restrict__ src, u16* __restrict__ dst) {
  int tid = blockIdx.x * blockDim.x + threadIdx.x;
  int e = tid * 4;
  float4 v = *(const float4*)(src + e);
  ushort4 o;
  o.x = f2bf(v.x); o.y = f2bf(v.y); o.z = f2bf(v.z); o.w = f2bf(v.w);
  *(ushort4*)(dst + e) = o;
}

// ---------------- 256-tile phased GEMM: C = scale * A * B^T ----------------
// BM=256, BK=64, 8 waves. BN=256: waves 2x4 (wave tile 128x64). BN=128: waves 4x2 (64x64).
// LDS rows are 128B, XOR-swizzled: storage(row, cb) = row*128 + (cb ^ ((row&7)<<4)).
// Staged via global_load_lds with pre-swizzled SOURCE (linear dest), double-buffered.
// A: [z][M][K] stride lda, batch elem-stride sA (bf16 or f16 per ABF16)
// B: [z][N][K] stride ldb, batch stride sB
// C: [z][M][N] stride ldc, batch stride sC; OUTM: 0=bf16, 1=f16, 2=f32
template <int BN, int ABF16, int OUTM>
__global__ __launch_bounds__(512, 2) void k_gemm256(
    const u16* __restrict__ A, const u16* __restrict__ B, void* __restrict__ Cv,
    int lda, int ldb, int ldc,
    long long sA, long long sB, long long sC,
    int K, float scale, int batches, int mtiles) {
  constexpr int M_rep = (BN == 256) ? 8 : 4;   // per-wave 16-row frags
  constexpr int WN = (BN == 256) ? 4 : 2;      // waves along N
  constexpr int NPH = (BN == 256) ? 4 : 2;     // phases per K-tile
  constexpr int A_BYTES = 256 * 128;           // 32 KB
  constexpr int B_BYTES = BN * 128;            // 32 / 16 KB
  constexpr int BUFB = A_BYTES + B_BYTES;
  constexpr int RND_A = A_BYTES / 8192;        // 4
  constexpr int RND_B = B_BYTES / 8192;        // 4 / 2
  constexpr int RNDS = RND_A + RND_B;          // 8 / 6
  constexpr int R_PER_PH = RNDS / NPH;         // 2 / 3

  __shared__ __align__(16) char lds[2 * BUFB];

  int t = threadIdx.x;
  int lane = t & 63;
  int w = t >> 6;
  int wr = w / WN, wc = w % WN;

  int bid = blockIdx.x;
  int z = bid % batches;
  int t2 = bid / batches;
  int tx = t2 % mtiles, ty = t2 / mtiles;

  const char* Ab = (const char*)(A + (long long)z * sA + (size_t)tx * 256 * lda);
  const char* Bb = (const char*)(B + (long long)z * sB + (size_t)ty * BN * ldb);
  size_t rsA = (size_t)lda * 2, rsB = (size_t)ldb * 2;

  // staging: round r covers 64 rows (8192 B). per-thread fixed (srow, scb).
  int srow = t >> 3;                 // row within 64-row round
  int ssb = (t & 7) * 16;            // storage byte within 128B row
  int scb = ssb ^ ((srow & 7) << 4); // logical byte (involution)

  auto stage = [&](int buf, int kt, int r) {
    int rr = (r < RND_A) ? r : r - RND_A;
    const char* gb = (r < RND_A) ? Ab : Bb;
    size_t rs = (r < RND_A) ? rsA : rsB;
    int ldsoff = (r < RND_A) ? 0 : A_BYTES;
    char* dst = lds + buf * BUFB + ldsoff + rr * 8192 + t * 16;
    gload_lds16(gb + (size_t)(rr * 64 + srow) * rs + (size_t)kt * 128 + scb, dst);
  };

  // per-thread read offsets
  int axor = (lane & 7) << 4;
  int arow0 = wr * (M_rep * 16) + (lane & 15);  // + m*16
  int brow0 = wc * 64 + (lane & 15);            // + n*16
  int kb0 = (lane >> 4) * 16;                   // + kk*64

  f32x4 acc[M_rep][4] = {};
  int NT = K >> 6;

  // prologue: stage tile 0 into buf 0
#pragma unroll
  for (int r = 0; r < RNDS; ++r) stage(0, 0, r);
  asm volatile("s_waitcnt vmcnt(0)" ::: "memory");
  __syncthreads();

  for (int kt = 0; kt < NT; ++kt) {
    int cur = kt & 1;
    bool do_stage = (kt + 1 < NT);
    const char* Abase = lds + cur * BUFB;
    const char* Bbase = Abase + A_BYTES;
    bf16x8 afr[4][2];
#pragma unroll
    for (int p = 0; p < NPH; ++p) {
      int mchunk = (p >> 1) * 4;
      int npair = (p & 1) * 2;
      // ds_read fragments (compiler inserts lgkmcnt before MFMA use)
      if ((p & 1) == 0) {
#pragma unroll
        for (int i = 0; i < 4; ++i)
#pragma unroll
          for (int kk = 0; kk < 2; ++kk)
            afr[i][kk] = *(const bf16x8*)(Abase + (arow0 + (mchunk + i) * 16) * 128 +
                                          ((kb0 + kk * 64) ^ axor));
      }
      bf16x8 bfr[2][2];
#pragma unroll
      for (int j = 0; j < 2; ++j)
#pragma unroll
        for (int kk = 0; kk < 2; ++kk)
          bfr[j][kk] = *(const bf16x8*)(Bbase + (brow0 + (npair + j) * 16) * 128 +
                                        ((kb0 + kk * 64) ^ axor));
      // stage next tile's half-tiles (issue early; drained at tile boundary)
      if (do_stage) {
#pragma unroll
        for (int q = 0; q < R_PER_PH; ++q) stage(cur ^ 1, kt + 1, p * R_PER_PH + q);
      }
      __builtin_amdgcn_sched_barrier(0);
      __builtin_amdgcn_s_barrier();
      __builtin_amdgcn_sched_barrier(0);
      __builtin_amdgcn_s_setprio(1);
#pragma unroll
      for (int i = 0; i < 4; ++i)
#pragma unroll
        for (int j = 0; j < 2; ++j)
#pragma unroll
          for (int kk = 0; kk < 2; ++kk) {
            if constexpr (ABF16) {
              acc[mchunk + i][npair + j] = __builtin_amdgcn_mfma_f32_16x16x32_f16(
                  __builtin_bit_cast(f16x8, afr[i][kk]), __builtin_bit_cast(f16x8, bfr[j][kk]),
                  acc[mchunk + i][npair + j], 0, 0, 0);
            } else {
              acc[mchunk + i][npair + j] = __builtin_amdgcn_mfma_f32_16x16x32_bf16(
                  afr[i][kk], bfr[j][kk], acc[mchunk + i][npair + j], 0, 0, 0);
            }
          }
      __builtin_amdgcn_s_setprio(0);
      __builtin_amdgcn_sched_barrier(0);
      if (p == NPH - 1) asm volatile("s_waitcnt vmcnt(0)" ::: "memory");
      __builtin_amdgcn_s_barrier();
      __builtin_amdgcn_sched_barrier(0);
    }
  }

  // epilogue
#pragma unroll
  for (int m = 0; m < M_rep; ++m) {
    int row = tx * 256 + wr * (M_rep * 16) + m * 16 + ((lane >> 4) << 2);
#pragma unroll
    for (int n = 0; n < 4; ++n) {
      int col = ty * BN + wc * 64 + n * 16 + (lane & 15);
#pragma unroll
      for (int r = 0; r < 4; ++r) {
        float v = acc[m][n][r] * scale;
        size_t idx = (size_t)((long long)z * sC) + (size_t)(row + r) * ldc + col;
        if constexpr (OUTM == 0) ((u16*)Cv)[idx] = f2bf(v);
        else if constexpr (OUTM == 1) ((_Float16*)Cv)[idx] = (_Float16)v;
        else ((float*)Cv)[idx] = v;
      }
    }
  }
}

// ---------------- row softmax, f16 in-place, rows of 2048 ----------------
__global__ __launch_bounds__(256) void k_softmax_f16(_Float16* __restrict__ S) {
  int row = blockIdx.x * 4 + (threadIdx.x >> 6);
  int lane = threadIdx.x & 63;
  _Float16* Sr = S + (size_t)row * 2048;

  f16x8 v[4];
#pragma unroll
  for (int i = 0; i < 4; ++i) v[i] = *(const f16x8*)(Sr + i * 512 + lane * 8);

  float f[32];
#pragma unroll
  for (int i = 0; i < 4; ++i)
#pragma unroll
    for (int j = 0; j < 8; ++j) f[i * 8 + j] = (float)v[i][j];

  float mx = f[0];
#pragma unroll
  for (int i = 1; i < 32; ++i) mx = fmaxf(mx, f[i]);
#pragma unroll
  for (int off = 1; off < 64; off <<= 1) mx = fmaxf(mx, __shfl_xor(mx, off));

  float sum = 0.0f;
#pragma unroll
  for (int i = 0; i < 32; ++i) {
    f[i] = exp2f((f[i] - mx) * LOG2E);
    sum += f[i];
  }
#pragma unroll
  for (int off = 1; off < 64; off <<= 1) sum += __shfl_xor(sum, off);

  float inv = 1.0f / sum;
  f16x8 o[4];
#pragma unroll
  for (int i = 0; i < 4; ++i)
#pragma unroll
    for (int j = 0; j < 8; ++j) o[i][j] = (_Float16)(f[i * 8 + j] * inv);
#pragma unroll
  for (int i = 0; i < 4; ++i) *(f16x8*)(Sr + i * 512 + lane * 8) = o[i];
}

extern "C" void kernel_launch(void* const* d_in, const int* in_sizes, int n_in,
                              void* d_out, int out_size, void* d_ws, size_t ws_size,
                              hipStream_t stream) {
  const float* x = (const float*)d_in[0];
  const float* y = (const float*)d_in[1];
  const float* Wq = (const float*)d_in[2];
  const float* Wk = (const float*)d_in[3];
  const float* Wv = (const float*)d_in[4];
  float* out = (float*)d_out;

  char* p = (char*)d_ws;
  u16* QKb = (u16*)p; p += (size_t)16384 * 1024 * 2;  // Q cols 0-511, K cols 512-1023 (bf16)
  u16* VTh = (u16*)p; p += (size_t)16384 * 512 * 2;   // f16 payload [512][16384]
  u16* Wqkb = (u16*)p; p += (size_t)1024 * 512 * 2;   // [Wq;Wk]
  u16* Wvb = (u16*)p; p += (size_t)512 * 512 * 2;
  size_t base = (size_t)(p - (char*)d_ws);
  u16* xyb = (u16*)p;          // dead after VT projection
  _Float16* Sb = (_Float16*)p; // aliases xyb

  int nc = (ws_size >= base + (size_t)16384 * 2048 * 2) ? 1 : 2;
  int mrows = 2048 / nc;
  int mt = mrows / 256;

  // converts
  k_concat_bf16<<<8192, 256, 0, stream>>>(x, y, xyb);
  k_f32_to_bf16<<<256, 256, 0, stream>>>(Wq, Wqkb);
  k_f32_to_bf16<<<256, 256, 0, stream>>>(Wk, Wqkb + (size_t)512 * 512);
  k_f32_to_bf16<<<256, 256, 0, stream>>>(Wv, Wvb);

  // fused Q/K projection: [16384][1024] = xy @ [Wq;Wk]^T  (bf16 out)
  k_gemm256<256, 0, 0><<<256, 512, 0, stream>>>(
      xyb, Wqkb, QKb, 512, 512, 1024, 0, 0, 0, 512, 1.0f, 1, 64);
  // VT projection: [512][16384] = Wv @ xy^T  (f16 out)
  k_gemm256<128, 0, 1><<<256, 512, 0, stream>>>(
      Wvb, xyb, VTh, 512, 512, 16384, 0, 0, 0, 512, 1.0f, 1, 2);

  const float scale = 0.044194173824159216f;  // 1/sqrt(512)
  for (int c = 0; c < nc; ++c) {
    const u16* Qc = QKb + (size_t)c * mrows * 1024;
    // S = scale * Q K^T  (f16 out): per-batch [mrows][2048]
    k_gemm256<256, 0, 1><<<8 * mt * 8, 512, 0, stream>>>(
        Qc, QKb + 512, Sb, 1024, 1024, 2048,
        (long long)2048 * 1024, (long long)2048 * 1024, (long long)mrows * 2048,
        512, scale, 8, mt);
    // softmax in place
    k_softmax_f16<<<(8 * mrows) / 4, 256, 0, stream>>>(Sb);
    // O = P @ VT^T (f16 in, f32 out)
    k_gemm256<128, 1, 2><<<8 * mt * 4, 512, 0, stream>>>(
        (const u16*)Sb, VTh, out + (size_t)c * mrows * 512, 2048, 16384, 512,
        (long long)mrows * 2048, (long long)2048, (long long)2048 * 512,
        2048, 1.0f, 8, mt);
  }
}

// Round 4
// 157.508 us; speedup vs baseline: 1.8543x; 1.0855x over previous
//
#include <hip/hip_runtime.h>
#include <hip/hip_bf16.h>
#include <stdint.h>

typedef unsigned short u16;
typedef unsigned int u32;
typedef __bf16 bf16x8 __attribute__((ext_vector_type(8)));
typedef _Float16 f16x8 __attribute__((ext_vector_type(8)));
typedef float f32x4 __attribute__((ext_vector_type(4)));

#define LOG2E 1.4426950408889634f

__device__ __forceinline__ u16 f2bf(float f) {
  u32 u = __builtin_bit_cast(u32, f);
  u += 0x7FFFu + ((u >> 16) & 1u);
  return (u16)(u >> 16);
}

__device__ __forceinline__ void gload_lds16(const void* g, void* l) {
  __builtin_amdgcn_global_load_lds(
      (const __attribute__((address_space(1))) u32*)g,
      (__attribute__((address_space(3))) u32*)l, 16, 0, 0);
}

// ---------------- convert / concat ----------------
__global__ void k_concat_bf16(const float* __restrict__ x, const float* __restrict__ y,
                              u16* __restrict__ xyb) {
  int tid = blockIdx.x * blockDim.x + threadIdx.x;
  int e = tid * 4;
  int s = e >> 9;
  int d = e & 511;
  int b = s >> 11, r = s & 2047;
  const float* src = (r < 1024) ? (x + ((size_t)(b * 1024 + r) * 512 + d))
                                : (y + ((size_t)(b * 1024 + (r - 1024)) * 512 + d));
  float4 v = *(const float4*)src;
  ushort4 o;
  o.x = f2bf(v.x); o.y = f2bf(v.y); o.z = f2bf(v.z); o.w = f2bf(v.w);
  *(ushort4*)(xyb + e) = o;
}

// all three weight matrices in one launch: Wq,Wk -> Wqkb (stacked), Wv -> Wvb
__global__ void k_w_to_bf16(const float* __restrict__ Wq, const float* __restrict__ Wk,
                            const float* __restrict__ Wv,
                            u16* __restrict__ Wqkb, u16* __restrict__ Wvb) {
  int tid = blockIdx.x * blockDim.x + threadIdx.x;  // 196608 threads
  int which = tid >> 16;
  int e = (tid & 65535) * 4;
  const float* src = (which == 0) ? Wq : (which == 1) ? Wk : Wv;
  u16* dst = (which == 0) ? Wqkb : (which == 1) ? (Wqkb + 262144) : Wvb;
  float4 v = *(const float4*)(src + e);
  ushort4 o;
  o.x = f2bf(v.x); o.y = f2bf(v.y); o.z = f2bf(v.z); o.w = f2bf(v.w);
  *(ushort4*)(dst + e) = o;
}

// ---------------- 256-tile phased GEMM: C = scale * A * B^T ----------------
// BM=256, BK=64, 8 waves. BN=256: waves 2x4 (wave tile 128x64). BN=128: waves 4x2 (64x64).
// LDS rows are 128B, XOR-swizzled: storage(row, cb) = row*128 + (cb ^ ((row&7)<<4)).
// Staged via global_load_lds with pre-swizzled SOURCE (linear dest), double-buffered.
// Schedule: stage ALL of tile kt+1 at the TOP of tile kt; no interior barriers;
// single vmcnt(0)+barrier at tile end (loads have a whole tile of MFMA to land).
template <int BN, int ABF16, int OUTM>
__global__ __launch_bounds__(512, 2) void k_gemm256(
    const u16* __restrict__ A, const u16* __restrict__ B, void* __restrict__ Cv,
    int lda, int ldb, int ldc,
    long long sA, long long sB, long long sC,
    int K, float scale, int batches, int mtiles) {
  constexpr int M_rep = (BN == 256) ? 8 : 4;
  constexpr int WN = (BN == 256) ? 4 : 2;
  constexpr int NPH = (BN == 256) ? 4 : 2;
  constexpr int A_BYTES = 256 * 128;
  constexpr int B_BYTES = BN * 128;
  constexpr int BUFB = A_BYTES + B_BYTES;
  constexpr int RND_A = A_BYTES / 8192;  // 4
  constexpr int RND_B = B_BYTES / 8192;  // 4 / 2
  constexpr int RNDS = RND_A + RND_B;    // 8 / 6

  __shared__ __align__(16) char lds[2 * BUFB];

  int t = threadIdx.x;
  int lane = t & 63;
  int w = t >> 6;
  int wr = w / WN, wc = w % WN;

  int bid = blockIdx.x;
  int z = bid % batches;
  int t2 = bid / batches;
  int tx = t2 % mtiles, ty = t2 / mtiles;

  const char* Ab = (const char*)(A + (long long)z * sA + (size_t)tx * 256 * lda);
  const char* Bb = (const char*)(B + (long long)z * sB + (size_t)ty * BN * ldb);
  size_t rsA = (size_t)lda * 2, rsB = (size_t)ldb * 2;

  // staging: round r covers 64 rows (8192 B); per-thread fixed (srow, scb).
  int srow = t >> 3;
  int scb = ((t & 7) * 16) ^ ((srow & 7) << 4);  // pre-swizzled global col byte

  const char* gsrc[RNDS];
#pragma unroll
  for (int r = 0; r < RNDS; ++r) {
    if (r < RND_A) gsrc[r] = Ab + (size_t)(r * 64 + srow) * rsA + scb;
    else           gsrc[r] = Bb + (size_t)((r - RND_A) * 64 + srow) * rsB + scb;
  }

  auto stageAll = [&](int buf) {
#pragma unroll
    for (int r = 0; r < RNDS; ++r) {
      int off = ((r < RND_A) ? r * 8192 : A_BYTES + (r - RND_A) * 8192) + t * 16;
      gload_lds16(gsrc[r], lds + buf * BUFB + off);
      gsrc[r] += 128;  // advance one K-tile
    }
  };

  // per-thread read offsets
  int axor = (lane & 7) << 4;
  int arow0 = wr * (M_rep * 16) + (lane & 15);
  int brow0 = wc * 64 + (lane & 15);
  int kb0 = (lane >> 4) * 16;

  f32x4 acc[M_rep][4] = {};
  int NT = K >> 6;

  // prologue: stage tile 0
  stageAll(0);
  asm volatile("s_waitcnt vmcnt(0)" ::: "memory");
  __syncthreads();

  for (int kt = 0; kt < NT; ++kt) {
    const char* Abase = lds + (kt & 1) * BUFB;
    const char* Bbase = Abase + A_BYTES;
    // issue next tile's loads FIRST — they retire under this tile's compute
    if (kt + 1 < NT) stageAll((kt & 1) ^ 1);
    __builtin_amdgcn_sched_barrier(0);

    bf16x8 afr[4][2];
#pragma unroll
    for (int p = 0; p < NPH; ++p) {
      int mchunk = (p >> 1) * 4;
      int npair = (p & 1) * 2;
      if ((p & 1) == 0) {
#pragma unroll
        for (int i = 0; i < 4; ++i)
#pragma unroll
          for (int kk = 0; kk < 2; ++kk)
            afr[i][kk] = *(const bf16x8*)(Abase + (arow0 + (mchunk + i) * 16) * 128 +
                                          ((kb0 + kk * 64) ^ axor));
      }
      bf16x8 bfr[2][2];
#pragma unroll
      for (int j = 0; j < 2; ++j)
#pragma unroll
        for (int kk = 0; kk < 2; ++kk)
          bfr[j][kk] = *(const bf16x8*)(Bbase + (brow0 + (npair + j) * 16) * 128 +
                                        ((kb0 + kk * 64) ^ axor));
      __builtin_amdgcn_s_setprio(1);
#pragma unroll
      for (int i = 0; i < 4; ++i)
#pragma unroll
        for (int j = 0; j < 2; ++j)
#pragma unroll
          for (int kk = 0; kk < 2; ++kk) {
            if constexpr (ABF16) {
              acc[mchunk + i][npair + j] = __builtin_amdgcn_mfma_f32_16x16x32_f16(
                  __builtin_bit_cast(f16x8, afr[i][kk]), __builtin_bit_cast(f16x8, bfr[j][kk]),
                  acc[mchunk + i][npair + j], 0, 0, 0);
            } else {
              acc[mchunk + i][npair + j] = __builtin_amdgcn_mfma_f32_16x16x32_bf16(
                  afr[i][kk], bfr[j][kk], acc[mchunk + i][npair + j], 0, 0, 0);
            }
          }
      __builtin_amdgcn_s_setprio(0);
    }

    if (kt + 1 < NT) {
      asm volatile("s_waitcnt vmcnt(0)" ::: "memory");
      __syncthreads();
    }
  }

  // epilogue
#pragma unroll
  for (int m = 0; m < M_rep; ++m) {
    int row = tx * 256 + wr * (M_rep * 16) + m * 16 + ((lane >> 4) << 2);
#pragma unroll
    for (int n = 0; n < 4; ++n) {
      int col = ty * BN + wc * 64 + n * 16 + (lane & 15);
#pragma unroll
      for (int r = 0; r < 4; ++r) {
        float v = acc[m][n][r] * scale;
        size_t idx = (size_t)((long long)z * sC) + (size_t)(row + r) * ldc + col;
        if constexpr (OUTM == 0) ((u16*)Cv)[idx] = f2bf(v);
        else if constexpr (OUTM == 1) ((_Float16*)Cv)[idx] = (_Float16)v;
        else ((float*)Cv)[idx] = v;
      }
    }
  }
}

// ---------------- row softmax, f16 in-place, rows of 2048 ----------------
__global__ __launch_bounds__(256) void k_softmax_f16(_Float16* __restrict__ S) {
  int row = blockIdx.x * 4 + (threadIdx.x >> 6);
  int lane = threadIdx.x & 63;
  _Float16* Sr = S + (size_t)row * 2048;

  f16x8 v[4];
#pragma unroll
  for (int i = 0; i < 4; ++i) v[i] = *(const f16x8*)(Sr + i * 512 + lane * 8);

  float f[32];
#pragma unroll
  for (int i = 0; i < 4; ++i)
#pragma unroll
    for (int j = 0; j < 8; ++j) f[i * 8 + j] = (float)v[i][j];

  float mx = f[0];
#pragma unroll
  for (int i = 1; i < 32; ++i) mx = fmaxf(mx, f[i]);
#pragma unroll
  for (int off = 1; off < 64; off <<= 1) mx = fmaxf(mx, __shfl_xor(mx, off));

  float sum = 0.0f;
#pragma unroll
  for (int i = 0; i < 32; ++i) {
    f[i] = exp2f((f[i] - mx) * LOG2E);
    sum += f[i];
  }
#pragma unroll
  for (int off = 1; off < 64; off <<= 1) sum += __shfl_xor(sum, off);

  float inv = 1.0f / sum;
  f16x8 o[4];
#pragma unroll
  for (int i = 0; i < 4; ++i)
#pragma unroll
    for (int j = 0; j < 8; ++j) o[i][j] = (_Float16)(f[i * 8 + j] * inv);
#pragma unroll
  for (int i = 0; i < 4; ++i) *(f16x8*)(Sr + i * 512 + lane * 8) = o[i];
}

extern "C" void kernel_launch(void* const* d_in, const int* in_sizes, int n_in,
                              void* d_out, int out_size, void* d_ws, size_t ws_size,
                              hipStream_t stream) {
  const float* x = (const float*)d_in[0];
  const float* y = (const float*)d_in[1];
  const float* Wq = (const float*)d_in[2];
  const float* Wk = (const float*)d_in[3];
  const float* Wv = (const float*)d_in[4];
  float* out = (float*)d_out;

  char* p = (char*)d_ws;
  u16* QKb = (u16*)p; p += (size_t)16384 * 1024 * 2;  // Q cols 0-511, K cols 512-1023 (bf16)
  u16* VTh = (u16*)p; p += (size_t)16384 * 512 * 2;   // f16 payload [512][16384]
  u16* Wqkb = (u16*)p; p += (size_t)1024 * 512 * 2;   // [Wq;Wk]
  u16* Wvb = (u16*)p; p += (size_t)512 * 512 * 2;
  size_t base = (size_t)(p - (char*)d_ws);
  u16* xyb = (u16*)p;          // dead after VT projection
  _Float16* Sb = (_Float16*)p; // aliases xyb

  int nc = (ws_size >= base + (size_t)16384 * 2048 * 2) ? 1 : 2;
  int mrows = 2048 / nc;
  int mt = mrows / 256;

  // converts
  k_concat_bf16<<<8192, 256, 0, stream>>>(x, y, xyb);
  k_w_to_bf16<<<768, 256, 0, stream>>>(Wq, Wk, Wv, Wqkb, Wvb);

  // fused Q/K projection: [16384][1024] = xy @ [Wq;Wk]^T  (bf16 out)
  k_gemm256<256, 0, 0><<<256, 512, 0, stream>>>(
      xyb, Wqkb, QKb, 512, 512, 1024, 0, 0, 0, 512, 1.0f, 1, 64);
  // VT projection: [512][16384] = Wv @ xy^T  (f16 out)
  k_gemm256<128, 0, 1><<<256, 512, 0, stream>>>(
      Wvb, xyb, VTh, 512, 512, 16384, 0, 0, 0, 512, 1.0f, 1, 2);

  const float scale = 0.044194173824159216f;  // 1/sqrt(512)
  for (int c = 0; c < nc; ++c) {
    const u16* Qc = QKb + (size_t)c * mrows * 1024;
    // S = scale * Q K^T  (f16 out): per-batch [mrows][2048]
    k_gemm256<256, 0, 1><<<8 * mt * 8, 512, 0, stream>>>(
        Qc, QKb + 512, Sb, 1024, 1024, 2048,
        (long long)2048 * 1024, (long long)2048 * 1024, (long long)mrows * 2048,
        512, scale, 8, mt);
    // softmax in place
    k_softmax_f16<<<(8 * mrows) / 4, 256, 0, stream>>>(Sb);
    // O = P @ VT^T (f16 in, f32 out)
    k_gemm256<128, 1, 2><<<8 * mt * 4, 512, 0, stream>>>(
        (const u16*)Sb, VTh, out + (size_t)c * mrows * 512, 2048, 16384, 512,
        (long long)mrows * 2048, (long long)2048, (long long)2048 * 512,
        2048, 1.0f, 8, mt);
  }
}